// Round 1
// 527.541 us; speedup vs baseline: 1.0719x; 1.0719x over previous
//
#include <hip/hip_runtime.h>

// approxmatch EMD (Fan et al.) on MI355X, B=4, N=M=4096, layout (B,3,N).
// Round 7: LDS-port round.
// Theory: at RPW=2 each cost_fused block moves ~480KB through the LDS port
// (4 waves re-read the same staged columns) ≈ 19us/kernel at 85 B/cyc/CU,
// vs a ~12us VALU floor -> port-bound. Fixes:
//  - RPW 2->4 (RPB 16, grid 1024 = 4 blocks/CU exactly): column reads
//    amortized over 4 rows -> port ~7.8us < compute -> compute-bound.
//    Per-lane column traversal order unchanged -> bitwise-identical sums.
//  - Flush-to-zero culling (t<=2 only): exp2(x) == +0.0f exactly for
//    x < -160 (below denormal range), and ((2^x)^2)^2 == +0.0f for x < -40.
//    Wave-uniform __all() skip produces the exact same +0.0 contributions
//    the hardware exp would -> bitwise identical, skips 40-99% of the
//    transcendental work on early sweeps. Disabled (compiled out) for t>=3
//    where the check is net-negative.

#define NPTS 4096
#define BATCH 4
#define EMD_EPS 1e-9f
#define TILE 1024        // columns staged per LDS stage
#define RPW 4            // rows per wave, in registers
#define THREADS 256      // 4 waves
#define RPB 16           // rows per block = 4 waves * RPW
#define NBLK (NPTS / RPB)  // 256 row-blocks per batch

#define CULL_FULL -160.0f  // exp2(x) == +0.0f for all x < -160 (incl. denorm range)
#define CULL_PART -40.0f   // ((2^x)^2)^2 == +0.0f for all x < -40

typedef float v2f __attribute__((ext_vector_type(2)));

__device__ __forceinline__ float fexp2(float x) {
#if __has_builtin(__builtin_amdgcn_exp2f)
    return __builtin_amdgcn_exp2f(x);
#else
    return exp2f(x);
#endif
}
__device__ __forceinline__ float fsqrt(float x) {
#if __has_builtin(__builtin_amdgcn_sqrtf)
    return __builtin_amdgcn_sqrtf(x);
#else
    return __sqrtf(x);
#endif
}

__device__ __forceinline__ float wave_reduce(float v) {
    v += __shfl_xor(v, 32);
    v += __shfl_xor(v, 16);
    v += __shfl_xor(v, 8);
    v += __shfl_xor(v, 4);
    v += __shfl_xor(v, 2);
    v += __shfl_xor(v, 1);
    return v;
}

// ---------------------------------------------------------------- pass 1 (sweep 0 only)
// remainR == 1, so ratioL_k = 1 / (EPS + sum_l exp2(ls2*d)); also inits
// remainL = remainR = 1 and cost_part = 0 for its indices.
// ls2[0] = -23637: ~99.3% of 128-pair groups fully flush -> cull always on.
__global__ __launch_bounds__(THREADS, 4) void k_ratioL0(
        const float* __restrict__ xyz1, const float* __restrict__ xyz2,
        float* __restrict__ ratioL, float* __restrict__ remainL,
        float* __restrict__ remainR, float ls2) {
    const int b = blockIdx.y;
    const int tid = threadIdx.x;
    const int wave = tid >> 6;
    const int lane = tid & 63;
    const int row0 = blockIdx.x * RPB + wave * RPW;

    const float* x1 = xyz1 + b * 3 * NPTS;
    const float* x2 = xyz2 + b * 3 * NPTS;
    const float2* x2x = (const float2*)(x2);
    const float2* x2y = (const float2*)(x2 + NPTS);
    const float2* x2z = (const float2*)(x2 + 2 * NPTS);

    float px[RPW], py[RPW], pz[RPW];
    v2f acc[RPW];
#pragma unroll
    for (int r = 0; r < RPW; ++r) {
        px[r] = x1[row0 + r];
        py[r] = x1[NPTS + row0 + r];
        pz[r] = x1[2 * NPTS + row0 + r];
        acc[r] = (v2f)(0.0f);
    }
    __shared__ float4 sA[TILE / 2];   // x0,x1,y0,y1
    __shared__ float2 sZ[TILE / 2];   // z0,z1

    for (int c0 = 0; c0 < NPTS; c0 += TILE) {
        __syncthreads();
        for (int i = tid; i < TILE / 2; i += THREADS) {
            int e = c0 / 2 + i;
            float2 xx = x2x[e], yy = x2y[e];
            sA[i] = make_float4(xx.x, xx.y, yy.x, yy.y);
            sZ[i] = x2z[e];
        }
        __syncthreads();
#pragma unroll 2
        for (int j = 0; j < TILE / 128; ++j) {
            float4 a = sA[lane + 64 * j];
            float2 z = sZ[lane + 64 * j];
            v2f ax = {a.x, a.y}, ay = {a.z, a.w}, az = {z.x, z.y};
#pragma unroll
            for (int r = 0; r < RPW; ++r) {
                v2f dx = px[r] - ax, dy = py[r] - ay, dz = pz[r] - az;
                v2f d = dx * dx + dy * dy + dz * dz;
                v2f sd = ls2 * d;
                if (!__all(fmaxf(sd.x, sd.y) < CULL_FULL)) {
                    v2f e2 = {fexp2(sd.x), fexp2(sd.y)};
                    acc[r] += e2;
                }
            }
        }
    }
#pragma unroll
    for (int r = 0; r < RPW; ++r) {
        float s = wave_reduce(acc[r].x + acc[r].y);
        if (lane == 0) {
            int idx = b * NPTS + row0 + r;
            ratioL[idx] = 1.0f / (EMD_EPS + s);
            remainL[idx] = 1.0f;
            remainR[idx] = 1.0f;
        }
    }
}

// ---------------------------------------------------------------- pass 2
// per column l: s = sum_k e*ratioL_k ; sumr = remainR*s ;
// ratioR = min(remainR/(sumr+EPS),1)*remainR ; remainR = max(0, remainR-sumr)
template <bool CULL>
__global__ __launch_bounds__(THREADS, 4) void k_ratioR(
        const float* __restrict__ xyz1, const float* __restrict__ xyz2,
        const float* __restrict__ ratioL, float* __restrict__ ratioR,
        float* __restrict__ remainR, float ls2) {
    const int b = blockIdx.y;
    const int tid = threadIdx.x;
    const int wave = tid >> 6;
    const int lane = tid & 63;
    const int col0 = blockIdx.x * RPB + wave * RPW;

    const float* x1 = xyz1 + b * 3 * NPTS;
    const float* x2 = xyz2 + b * 3 * NPTS;
    const float2* x1x = (const float2*)(x1);
    const float2* x1y = (const float2*)(x1 + NPTS);
    const float2* x1z = (const float2*)(x1 + 2 * NPTS);
    const float2* wLv = (const float2*)(ratioL + b * NPTS);

    float px[RPW], py[RPW], pz[RPW];
    v2f acc[RPW];
#pragma unroll
    for (int r = 0; r < RPW; ++r) {
        px[r] = x2[col0 + r];
        py[r] = x2[NPTS + col0 + r];
        pz[r] = x2[2 * NPTS + col0 + r];
        acc[r] = (v2f)(0.0f);
    }
    __shared__ float4 sA[TILE / 2];   // x0,x1,y0,y1
    __shared__ float4 sB[TILE / 2];   // z0,z1,w0,w1

    for (int c0 = 0; c0 < NPTS; c0 += TILE) {
        __syncthreads();
        for (int i = tid; i < TILE / 2; i += THREADS) {
            int e = c0 / 2 + i;
            float2 xx = x1x[e], yy = x1y[e], zz = x1z[e], ww = wLv[e];
            sA[i] = make_float4(xx.x, xx.y, yy.x, yy.y);
            sB[i] = make_float4(zz.x, zz.y, ww.x, ww.y);
        }
        __syncthreads();
#pragma unroll 2
        for (int j = 0; j < TILE / 128; ++j) {
            float4 a = sA[lane + 64 * j];
            float4 bq = sB[lane + 64 * j];
            v2f ax = {a.x, a.y}, ay = {a.z, a.w};
            v2f az = {bq.x, bq.y}, aw = {bq.z, bq.w};
#pragma unroll
            for (int r = 0; r < RPW; ++r) {
                v2f dx = px[r] - ax, dy = py[r] - ay, dz = pz[r] - az;
                v2f d = dx * dx + dy * dy + dz * dz;
                v2f sd = ls2 * d;
                bool live = true;
                if (CULL) live = !__all(fmaxf(sd.x, sd.y) < CULL_FULL);
                if (live) {
                    v2f e2 = {fexp2(sd.x), fexp2(sd.y)};
                    acc[r] += e2 * aw;
                }
            }
        }
    }
#pragma unroll
    for (int r = 0; r < RPW; ++r) {
        float s = wave_reduce(acc[r].x + acc[r].y);
        if (lane == 0) {
            int idx = b * NPTS + col0 + r;
            float rv = remainR[idx];
            float sumr = rv * s;
            float cons = fminf(rv / (sumr + EMD_EPS), 1.0f);
            ratioR[idx] = cons * rv;
            remainR[idx] = fmaxf(0.0f, rv - sumr);
        }
    }
}

// ---------------------------------------------------------------- pass 3(t) + pass 1(t+1) fused
// SQ: e2 = exp2(ls2n*d); er = e2^4 * ratioR (ls2 == 4*ls2n exactly).
// !SQ (t=8): er = exp2(ls2*d)*ratioR, e2 == 1 (ls2n == 0).
// acc_a = sum er ; acc_c = sum er*sqrt(d) ; acc_s = sum e2*remainR
// CULL tiers (exact): sd_n < -160 -> e2 == +0 -> whole body is +0.
//                     sd_n < -40  -> e2^4 == +0 -> er path is +0, keep acc_s.
template <bool SQ, bool CULL>
__global__ __launch_bounds__(THREADS, 4) void k_cost_fused(
        const float* __restrict__ xyz1, const float* __restrict__ xyz2,
        float* __restrict__ ratioL, const float* __restrict__ ratioR,
        float* __restrict__ remainL, const float* __restrict__ remainR,
        float* __restrict__ cost_part, float ls2, float ls2n, int initCost) {
    const int b = blockIdx.y;
    const int tid = threadIdx.x;
    const int wave = tid >> 6;
    const int lane = tid & 63;
    const int row0 = blockIdx.x * RPB + wave * RPW;

    const float* x1 = xyz1 + b * 3 * NPTS;
    const float* x2 = xyz2 + b * 3 * NPTS;
    const float2* x2x = (const float2*)(x2);
    const float2* x2y = (const float2*)(x2 + NPTS);
    const float2* x2z = (const float2*)(x2 + 2 * NPTS);
    const float2* wRv = (const float2*)(ratioR + b * NPTS);
    const float2* w2v = (const float2*)(remainR + b * NPTS);

    float px[RPW], py[RPW], pz[RPW];
    v2f acc_a[RPW], acc_c[RPW], acc_s[RPW];
#pragma unroll
    for (int r = 0; r < RPW; ++r) {
        px[r] = x1[row0 + r];
        py[r] = x1[NPTS + row0 + r];
        pz[r] = x1[2 * NPTS + row0 + r];
        acc_a[r] = (v2f)(0.0f);
        acc_c[r] = (v2f)(0.0f);
        acc_s[r] = (v2f)(0.0f);
    }
    __shared__ float4 sA[TILE / 2];   // x0,x1,y0,y1
    __shared__ float4 sB[TILE / 2];   // z0,z1,wR0,wR1
    __shared__ float2 sC[TILE / 2];   // w20,w21
    __shared__ float s_cost[THREADS / 64];

    for (int c0 = 0; c0 < NPTS; c0 += TILE) {
        __syncthreads();
        for (int i = tid; i < TILE / 2; i += THREADS) {
            int e = c0 / 2 + i;
            float2 xx = x2x[e], yy = x2y[e], zz = x2z[e], wr = wRv[e];
            sA[i] = make_float4(xx.x, xx.y, yy.x, yy.y);
            sB[i] = make_float4(zz.x, zz.y, wr.x, wr.y);
            sC[i] = w2v[e];
        }
        __syncthreads();
#pragma unroll 2
        for (int j = 0; j < TILE / 128; ++j) {
            float4 a = sA[lane + 64 * j];
            float4 bq = sB[lane + 64 * j];
            float2 c = sC[lane + 64 * j];
            v2f ax = {a.x, a.y}, ay = {a.z, a.w};
            v2f az = {bq.x, bq.y}, wr = {bq.z, bq.w};
            v2f cw = {c.x, c.y};
#pragma unroll
            for (int r = 0; r < RPW; ++r) {
                v2f dx = px[r] - ax, dy = py[r] - ay, dz = pz[r] - az;
                v2f d = dx * dx + dy * dy + dz * dz;
                if (SQ) {
                    v2f sd = ls2n * d;
                    bool fullskip = false, partskip = false;
                    if (CULL) {
                        float mx = fmaxf(sd.x, sd.y);
                        fullskip = __all(mx < CULL_FULL);
                        partskip = __all(mx < CULL_PART);
                    }
                    if (!fullskip) {
                        v2f e2 = {fexp2(sd.x), fexp2(sd.y)};
                        acc_s[r] += e2 * cw;
                        if (!partskip) {
                            v2f e4 = e2 * e2;
                            v2f er = (e4 * e4) * wr;
                            acc_a[r] += er;
                            v2f sq = {fsqrt(d.x), fsqrt(d.y)};
                            acc_c[r] += er * sq;
                        }
                    }
                } else {
                    v2f sd = ls2 * d;
                    v2f e1 = {fexp2(sd.x), fexp2(sd.y)};
                    v2f er = e1 * wr;
                    acc_s[r] += cw;   // e2 == 1 when ls2n == 0
                    acc_a[r] += er;
                    v2f sq = {fsqrt(d.x), fsqrt(d.y)};
                    acc_c[r] += er * sq;
                }
            }
        }
    }
    float wcost = 0.0f;
#pragma unroll
    for (int r = 0; r < RPW; ++r) {
        float sa = wave_reduce(acc_a[r].x + acc_a[r].y);
        float sc = wave_reduce(acc_c[r].x + acc_c[r].y);
        float ss = wave_reduce(acc_s[r].x + acc_s[r].y);
        if (lane == 0) {
            int idx = b * NPTS + row0 + r;
            float rl = ratioL[idx];
            float rem = fmaxf(0.0f, remainL[idx] - rl * sa);
            remainL[idx] = rem;
            ratioL[idx] = rem / (EMD_EPS + ss);   // next sweep's ratioL
            wcost = fmaf(rl, sc, wcost);
        }
    }
    if (lane == 0) s_cost[wave] = wcost;
    __syncthreads();
    if (tid == 0) {
        float t = s_cost[0] + s_cost[1] + s_cost[2] + s_cost[3];
        int ci = b * NBLK + blockIdx.x;
        cost_part[ci] = (initCost ? t : cost_part[ci] + t);
    }
}

// ---------------------------------------------------------------- level-0
__global__ void k_sum_ratioL(const float* __restrict__ ratioL, float* __restrict__ S_L) {
    const int b = blockIdx.x;
    const int tid = threadIdx.x;
    float s = 0.0f;
    for (int i = tid; i < NPTS; i += 256) s += ratioL[b * NPTS + i];
    s = wave_reduce(s);
    __shared__ float sw[4];
    if ((tid & 63) == 0) sw[tid >> 6] = s;
    __syncthreads();
    if (tid == 0) S_L[b] = sw[0] + sw[1] + sw[2] + sw[3];
}

// level-0 cost pass: e == 1. ratioR computed inline during staging from
// remainR and S_L.
__global__ __launch_bounds__(THREADS, 4) void k_cost_l0(
        const float* __restrict__ xyz1, const float* __restrict__ xyz2,
        const float* __restrict__ ratioL, const float* __restrict__ remainR,
        const float* __restrict__ S_L, float* __restrict__ cost_part) {
    const int b = blockIdx.y;
    const int tid = threadIdx.x;
    const int wave = tid >> 6;
    const int lane = tid & 63;
    const int row0 = blockIdx.x * RPB + wave * RPW;
    const float sL = S_L[b];

    const float* x1 = xyz1 + b * 3 * NPTS;
    const float* x2 = xyz2 + b * 3 * NPTS;
    const float2* x2x = (const float2*)(x2);
    const float2* x2y = (const float2*)(x2 + NPTS);
    const float2* x2z = (const float2*)(x2 + 2 * NPTS);
    const float2* wRv = (const float2*)(remainR + b * NPTS);

    float px[RPW], py[RPW], pz[RPW];
    v2f acc_c[RPW];
#pragma unroll
    for (int r = 0; r < RPW; ++r) {
        px[r] = x1[row0 + r];
        py[r] = x1[NPTS + row0 + r];
        pz[r] = x1[2 * NPTS + row0 + r];
        acc_c[r] = (v2f)(0.0f);
    }
    __shared__ float4 sA[TILE / 2];
    __shared__ float4 sB[TILE / 2];
    __shared__ float s_cost[THREADS / 64];

    for (int c0 = 0; c0 < NPTS; c0 += TILE) {
        __syncthreads();
        for (int i = tid; i < TILE / 2; i += THREADS) {
            int e = c0 / 2 + i;
            float2 xx = x2x[e], yy = x2y[e], zz = x2z[e], rv = wRv[e];
            // ratioR_l0 inline: sumr = rv*S_L; wr = min(rv/(sumr+eps),1)*rv
            float wr0 = fminf(rv.x / (rv.x * sL + EMD_EPS), 1.0f) * rv.x;
            float wr1 = fminf(rv.y / (rv.y * sL + EMD_EPS), 1.0f) * rv.y;
            sA[i] = make_float4(xx.x, xx.y, yy.x, yy.y);
            sB[i] = make_float4(zz.x, zz.y, wr0, wr1);
        }
        __syncthreads();
#pragma unroll 2
        for (int j = 0; j < TILE / 128; ++j) {
            float4 a = sA[lane + 64 * j];
            float4 bq = sB[lane + 64 * j];
            v2f ax = {a.x, a.y}, ay = {a.z, a.w};
            v2f az = {bq.x, bq.y}, wr = {bq.z, bq.w};
#pragma unroll
            for (int r = 0; r < RPW; ++r) {
                v2f dx = px[r] - ax, dy = py[r] - ay, dz = pz[r] - az;
                v2f d = dx * dx + dy * dy + dz * dz;
                v2f sq = {fsqrt(d.x), fsqrt(d.y)};
                acc_c[r] += wr * sq;
            }
        }
    }
    float wcost = 0.0f;
#pragma unroll
    for (int r = 0; r < RPW; ++r) {
        float sc = wave_reduce(acc_c[r].x + acc_c[r].y);
        if (lane == 0)
            wcost = fmaf(ratioL[b * NPTS + row0 + r], sc, wcost);
    }
    if (lane == 0) s_cost[wave] = wcost;
    __syncthreads();
    if (tid == 0) {
        float t = s_cost[0] + s_cost[1] + s_cost[2] + s_cost[3];
        cost_part[b * NBLK + blockIdx.x] += t;
    }
}

// ---------------------------------------------------------------- finalize
__global__ void k_final(const float* __restrict__ cost_part, float* __restrict__ out) {
    const int tid = threadIdx.x;
    float s = 0.0f;
    for (int i = tid; i < BATCH * NBLK; i += 256) s += cost_part[i];
    s = wave_reduce(s);
    __shared__ float sw[4];
    if ((tid & 63) == 0) sw[tid >> 6] = s;
    __syncthreads();
    if (tid == 0) out[0] = (sw[0] + sw[1] + sw[2] + sw[3]) / ((float)NPTS * (float)BATCH);
}

extern "C" void kernel_launch(void* const* d_in, const int* in_sizes, int n_in,
                              void* d_out, int out_size, void* d_ws, size_t ws_size,
                              hipStream_t stream) {
    const float* xyz1 = (const float*)d_in[0];
    const float* xyz2 = (const float*)d_in[1];
    float* out = (float*)d_out;

    const int BN = BATCH * NPTS;
    float* ws = (float*)d_ws;
    float* remainL  = ws;                      // BN
    float* remainR  = ws + 1 * BN;             // BN
    float* ratioL   = ws + 2 * BN;             // BN
    float* ratioR   = ws + 3 * BN;             // BN
    float* cost_part = ws + 4 * BN;            // BATCH*NBLK = 1024
    float* S_L      = cost_part + BATCH * NBLK;  // BATCH

    // levels: -(4^j) for j = 7..-1, then 0; premultiplied by log2(e).
    // Consecutive levels differ by exactly 4x -> ls2[t] == 4*ls2[t+1] exactly.
    static const float levels[10] = {
        -16384.0f, -4096.0f, -1024.0f, -256.0f, -64.0f,
        -16.0f, -4.0f, -1.0f, -0.25f, 0.0f};
    float ls2[10];
    for (int t = 0; t < 10; ++t)
        ls2[t] = (float)(levels[t] * 1.4426950408889634);

    dim3 grid(NBLK, BATCH);

    k_ratioL0<<<grid, THREADS, 0, stream>>>(xyz1, xyz2, ratioL, remainL, remainR, ls2[0]);
    for (int t = 0; t < 8; ++t) {
        if (t < 3) {
            k_ratioR<true><<<grid, THREADS, 0, stream>>>(xyz1, xyz2, ratioL, ratioR,
                                                         remainR, ls2[t]);
            k_cost_fused<true, true><<<grid, THREADS, 0, stream>>>(
                xyz1, xyz2, ratioL, ratioR, remainL, remainR, cost_part,
                ls2[t], ls2[t + 1], t == 0 ? 1 : 0);
        } else {
            k_ratioR<false><<<grid, THREADS, 0, stream>>>(xyz1, xyz2, ratioL, ratioR,
                                                          remainR, ls2[t]);
            k_cost_fused<true, false><<<grid, THREADS, 0, stream>>>(
                xyz1, xyz2, ratioL, ratioR, remainL, remainR, cost_part,
                ls2[t], ls2[t + 1], 0);
        }
    }
    // t = 8: next level is 0 (no 4x relation) -> direct-exp variant
    k_ratioR<false><<<grid, THREADS, 0, stream>>>(xyz1, xyz2, ratioL, ratioR,
                                                  remainR, ls2[8]);
    k_cost_fused<false, false><<<grid, THREADS, 0, stream>>>(
        xyz1, xyz2, ratioL, ratioR, remainL, remainR, cost_part, ls2[8], 0.0f, 0);
    // sweep 9 (level == 0): suml handled by acc_s above; ratioR inline in cost_l0
    k_sum_ratioL<<<BATCH, 256, 0, stream>>>(ratioL, S_L);
    k_cost_l0<<<grid, THREADS, 0, stream>>>(xyz1, xyz2, ratioL, remainR, S_L, cost_part);
    k_final<<<1, 256, 0, stream>>>(cost_part, out);
}